// Round 1
// baseline (79.168 us; speedup 1.0000x reference)
//
#include <hip/hip_runtime.h>

// Chamfer distance, bidirectional, fp32.
// pred/tgt: (16, 2048, 3) fp32. Output: scalar fp32.
//
// Grid decomposition:
//   blockIdx.x in [0, 1024): dir (2) x batch (16) x chunk (32).
//   Each block: 64 query points (one per lane), 4 waves each scanning a
//   disjoint 512-point range of the "other" cloud (wave-uniform addresses
//   -> scalar loads), LDS combine of the 4 partial mins, block sum,
//   one atomicAdd of (sum / 32768) into out[0].

#define NPTS  2048
#define BATCH 16

__global__ __launch_bounds__(256) void chamfer_kernel(
    const float* __restrict__ pred,
    const float* __restrict__ tgt,
    float* __restrict__ out)
{
    const int bid   = blockIdx.x;
    const int dir   = bid >> 9;        // 0: pred->tgt, 1: tgt->pred
    const int rem   = bid & 511;
    const int b     = rem >> 5;        // batch index 0..15
    const int chunk = rem & 31;        // 32 chunks of 64 points

    const int lane = threadIdx.x & 63;
    const int w    = threadIdx.x >> 6; // wave id 0..3

    const float* __restrict__ P = (dir == 0) ? pred : tgt;  // query cloud
    const float* __restrict__ T = (dir == 0) ? tgt  : pred; // other cloud

    const float* Pb = P + (size_t)b * NPTS * 3;
    const float* Tb = T + (size_t)b * NPTS * 3;

    // My query point (one per lane), held in registers.
    const int pi   = chunk * 64 + lane;
    const float px = Pb[pi * 3 + 0];
    const float py = Pb[pi * 3 + 1];
    const float pz = Pb[pi * 3 + 2];

    float m = 3.4e38f;

    // Wave-uniform scan of 512 "other" points.
    const int j0 = w * 512;
    #pragma unroll 4
    for (int j = j0; j < j0 + 512; ++j) {
        const float tx = Tb[j * 3 + 0];
        const float ty = Tb[j * 3 + 1];
        const float tz = Tb[j * 3 + 2];
        const float dx = px - tx;
        const float dy = py - ty;
        const float dz = pz - tz;
        const float d2 = dx * dx + dy * dy + dz * dz; // mul + 2 fma
        m = fminf(m, d2);
    }

    // Combine the 4 per-wave partial mins (same 64 points, disjoint ranges).
    __shared__ float smin[4][64];
    smin[w][lane] = m;
    __syncthreads();

    if (w == 0) {
        float v = fminf(fminf(smin[0][lane], smin[1][lane]),
                        fminf(smin[2][lane], smin[3][lane]));
        // Sum the 64 per-point mins across the wave.
        #pragma unroll
        for (int off = 32; off > 0; off >>= 1)
            v += __shfl_down(v, off);
        if (lane == 0)
            atomicAdd(out, v * (1.0f / (float)(BATCH * NPTS)));
    }
}

extern "C" void kernel_launch(void* const* d_in, const int* in_sizes, int n_in,
                              void* d_out, int out_size, void* d_ws, size_t ws_size,
                              hipStream_t stream)
{
    const float* pred = (const float*)d_in[0];
    const float* tgt  = (const float*)d_in[1];
    float* out = (float*)d_out;

    // Harness poisons d_out once and never re-poisons between replays:
    // zero it every call so the atomic accumulation starts clean.
    hipMemsetAsync(out, 0, sizeof(float), stream);

    chamfer_kernel<<<dim3(1024), dim3(256), 0, stream>>>(pred, tgt, out);
}

// Round 2
// 36.604 us; speedup vs baseline: 2.1628x; 2.1628x over previous
//
#include <hip/hip_runtime.h>

// Bidirectional Chamfer distance, fp32, shapes (16, 2048, 3).
//
// Grid: 256 blocks = dir(2) x batch(16) x query-chunk(8).
// Block: 512 threads = 8 waves. All waves share one 256-query group
// (4 queries per lane in registers); wave w scans target slice
// [w*256, w*256+256) from a 32 KB LDS tile of float4 (x,y,z,|t|^2).
//
// Math trick: d2 = |p|^2 + |t|^2 - 2 p.t. Track m = min(|t|^2 - 2 p.t)
// (5 VALU/pair: mul, fma, fma, fma, min) and add |p|^2 after the scan.
// |t|^2 rides in the float4's .w slot (computed once during staging).

#define NPTS  2048
#define BATCH 16

__global__ __launch_bounds__(512) void chamfer_kernel(
    const float* __restrict__ pred,
    const float* __restrict__ tgt,
    float* __restrict__ out)
{
    const int bid = blockIdx.x;
    const int dir = bid >> 7;          // 0: pred->tgt, 1: tgt->pred
    const int b   = (bid >> 3) & 15;   // batch
    const int qc  = bid & 7;           // query chunk of 256

    const int tid  = threadIdx.x;
    const int lane = tid & 63;
    const int w    = tid >> 6;         // wave 0..7

    const float* __restrict__ P = dir ? tgt  : pred;  // query cloud
    const float* __restrict__ T = dir ? pred : tgt;   // other cloud
    const float* Pb = P + (size_t)b * NPTS * 3;
    const float* Tb = T + (size_t)b * NPTS * 3;

    __shared__ float4 tile[NPTS];      // 32 KB: x, y, z, |t|^2
    __shared__ float  smin[8][256];    // 8 KB: per-wave partial mins

    // --- Stage the full target cloud into LDS (4 points per thread) ---
    #pragma unroll
    for (int k = 0; k < 4; ++k) {
        const int idx = tid + k * 512;
        const float x = Tb[idx * 3 + 0];
        const float y = Tb[idx * 3 + 1];
        const float z = Tb[idx * 3 + 2];
        tile[idx] = make_float4(x, y, z, x * x + y * y + z * z);
    }

    // --- Load 4 query points per lane into registers ---
    float px[4], py[4], pz[4], pp[4], m[4];
    #pragma unroll
    for (int q = 0; q < 4; ++q) {
        const int qi = qc * 256 + q * 64 + lane;
        px[q] = Pb[qi * 3 + 0];
        py[q] = Pb[qi * 3 + 1];
        pz[q] = Pb[qi * 3 + 2];
        pp[q] = px[q] * px[q] + py[q] * py[q] + pz[q] * pz[q];
        m[q]  = 3.4e38f;
    }

    __syncthreads();

    // --- Scan this wave's 256-target slice (broadcast ds_read_b128) ---
    const int t0 = w * 256;
    #pragma unroll 8
    for (int j = 0; j < 256; ++j) {
        const float4 t = tile[t0 + j];
        #pragma unroll
        for (int q = 0; q < 4; ++q) {
            const float s = fmaf(pz[q], t.z, fmaf(py[q], t.y, px[q] * t.x));
            m[q] = fminf(m[q], fmaf(s, -2.0f, t.w));   // |t|^2 - 2 p.t
        }
    }

    // --- Cross-wave min combine (add |p|^2 here: commutes with min) ---
    #pragma unroll
    for (int q = 0; q < 4; ++q)
        smin[w][q * 64 + lane] = m[q] + pp[q];
    __syncthreads();

    if (tid < 256) {
        float v = smin[0][tid];
        #pragma unroll
        for (int ww = 1; ww < 8; ++ww)
            v = fminf(v, smin[ww][tid]);
        // Sum the 64 query mins in this wave, one atomic per wave.
        #pragma unroll
        for (int off = 32; off > 0; off >>= 1)
            v += __shfl_down(v, off);
        if (lane == 0)
            atomicAdd(out, v * (1.0f / (float)(BATCH * NPTS)));
    }
}

extern "C" void kernel_launch(void* const* d_in, const int* in_sizes, int n_in,
                              void* d_out, int out_size, void* d_ws, size_t ws_size,
                              hipStream_t stream)
{
    const float* pred = (const float*)d_in[0];
    const float* tgt  = (const float*)d_in[1];
    float* out = (float*)d_out;

    // Harness poisons d_out once and never re-poisons between replays:
    // zero it every call so the atomic accumulation starts clean.
    hipMemsetAsync(out, 0, sizeof(float), stream);

    chamfer_kernel<<<dim3(256), dim3(512), 0, stream>>>(pred, tgt, out);
}

// Round 3
// 33.357 us; speedup vs baseline: 2.3733x; 1.0973x over previous
//
#include <hip/hip_runtime.h>

// Bidirectional Chamfer distance, fp32, shapes (16, 2048, 3).
//
// Grid: 256 blocks = dir(2) x batch(16) x query-chunk(8)  -> 1 block/CU.
// Block: 1024 threads = 16 waves (4 waves/SIMD for latency hiding).
// All waves share one 256-query group (Q=4 queries/lane in registers);
// wave w scans target slice [w*128, w*128+128) from a 32 KB LDS tile of
// float4 (x, y, z, |t|^2) via broadcast ds_read_b128 (no bank conflicts).
//
// Math: d2 = |p|^2 + |t|^2 - 2 p.t. Precompute q = -2p per lane, track
// m = min_j fma(qz,tz, fma(qy,ty, fma(qx,tx, |t|^2)))  -- 4 VALU/pair
// (3 fma + 1 min) -- and add |p|^2 once after the scan (commutes with min).
// Two min accumulators (even/odd j) double the independent chains.

#define NPTS  2048
#define BATCH 16

__global__ __launch_bounds__(1024) void chamfer_kernel(
    const float* __restrict__ pred,
    const float* __restrict__ tgt,
    float* __restrict__ out)
{
    const int bid = blockIdx.x;
    const int dir = bid >> 7;          // 0: pred->tgt, 1: tgt->pred
    const int b   = (bid >> 3) & 15;   // batch
    const int qc  = bid & 7;           // query chunk of 256

    const int tid  = threadIdx.x;
    const int lane = tid & 63;
    const int w    = tid >> 6;         // wave 0..15

    const float* __restrict__ P = dir ? tgt  : pred;  // query cloud
    const float* __restrict__ T = dir ? pred : tgt;   // other cloud
    const float* Pb = P + (size_t)b * NPTS * 3;
    const float* Tb = T + (size_t)b * NPTS * 3;

    __shared__ float4 tile[NPTS];      // 32 KB: x, y, z, |t|^2
    __shared__ float  smin[16][256];   // 16 KB: per-wave partial mins

    // --- Stage the full target cloud into LDS (2 points per thread) ---
    #pragma unroll
    for (int k = 0; k < 2; ++k) {
        const int idx = tid + k * 1024;
        const float x = Tb[idx * 3 + 0];
        const float y = Tb[idx * 3 + 1];
        const float z = Tb[idx * 3 + 2];
        tile[idx] = make_float4(x, y, z, x * x + y * y + z * z);
    }

    // --- Load 4 query points per lane; fold -2 into the query ---
    float qx[4], qy[4], qz[4], pp[4], m0[4], m1[4];
    #pragma unroll
    for (int q = 0; q < 4; ++q) {
        const int qi = qc * 256 + q * 64 + lane;
        const float x = Pb[qi * 3 + 0];
        const float y = Pb[qi * 3 + 1];
        const float z = Pb[qi * 3 + 2];
        qx[q] = -2.0f * x;
        qy[q] = -2.0f * y;
        qz[q] = -2.0f * z;
        pp[q] = x * x + y * y + z * z;
        m0[q] = 3.4e38f;
        m1[q] = 3.4e38f;
    }

    __syncthreads();

    // --- Scan this wave's 128-target slice ---
    const int base = w * 128;
    #pragma unroll 4
    for (int j = 0; j < 128; j += 2) {
        const float4 ta = tile[base + j];
        const float4 tb = tile[base + j + 1];
        #pragma unroll
        for (int q = 0; q < 4; ++q) {
            m0[q] = fminf(m0[q],
                fmaf(qz[q], ta.z, fmaf(qy[q], ta.y, fmaf(qx[q], ta.x, ta.w))));
            m1[q] = fminf(m1[q],
                fmaf(qz[q], tb.z, fmaf(qy[q], tb.y, fmaf(qx[q], tb.x, tb.w))));
        }
    }

    // --- Cross-wave min combine (add |p|^2 here: commutes with min) ---
    #pragma unroll
    for (int q = 0; q < 4; ++q)
        smin[w][q * 64 + lane] = fminf(m0[q], m1[q]) + pp[q];
    __syncthreads();

    if (tid < 256) {
        float v = smin[0][tid];
        #pragma unroll
        for (int ww = 1; ww < 16; ++ww)
            v = fminf(v, smin[ww][tid]);
        // Sum the 64 query mins in this wave, one atomic per wave.
        #pragma unroll
        for (int off = 32; off > 0; off >>= 1)
            v += __shfl_down(v, off);
        if (lane == 0)
            atomicAdd(out, v * (1.0f / (float)(BATCH * NPTS)));
    }
}

extern "C" void kernel_launch(void* const* d_in, const int* in_sizes, int n_in,
                              void* d_out, int out_size, void* d_ws, size_t ws_size,
                              hipStream_t stream)
{
    const float* pred = (const float*)d_in[0];
    const float* tgt  = (const float*)d_in[1];
    float* out = (float*)d_out;

    // Harness poisons d_out once and never re-poisons between replays:
    // zero it every call so the atomic accumulation starts clean.
    hipMemsetAsync(out, 0, sizeof(float), stream);

    chamfer_kernel<<<dim3(256), dim3(1024), 0, stream>>>(pred, tgt, out);
}